// Round 1
// baseline (504.084 us; speedup 1.0000x reference)
//
#include <hip/hip_runtime.h>
#include <math.h>

#define EPS 1e-5f

constexpr int T_   = 4 * 512;   // 2048 tokens
constexpr int IN_  = 256;
constexpr int OUT_ = 256;
constexpr int HID_ = 32;

// ---------------------------------------------------------------------------
// Kernel A: per token t (one 64-thread block each):
//   hw[t,h]  = x[t,:]·w1[h,:] + b1[h]          (h<32, thread h)
//   hb[h]    = x[t,:]·u1[h,:] + c1[h]          (thread h+32, kept in LDS)
//   bvec[o]  = hb·u2[o,:] + c2[o]; b_ln = LN_o(bvec)  (thread l owns o=4l..4l+3)
// ---------------------------------------------------------------------------
__global__ __launch_bounds__(64)
void ka_hw_bias(const float* __restrict__ x,
                const float* __restrict__ w1, const float* __restrict__ b1,
                const float* __restrict__ u1, const float* __restrict__ c1,
                const float* __restrict__ u2, const float* __restrict__ c2,
                float* __restrict__ hw_out,   // [T,32]
                float* __restrict__ bln_out)  // [T,256]
{
    const int t = blockIdx.x;
    const int l = threadIdx.x;

    __shared__ float xs[IN_];
    __shared__ float hb[HID_];

    // stage x row (64 lanes * float4 = 256 floats)
    reinterpret_cast<float4*>(xs)[l] =
        reinterpret_cast<const float4*>(x + (size_t)t * IN_)[l];
    __syncthreads();

    // hw (threads 0..31) / hb (threads 32..63)
    const float* wrow = (l < 32) ? (w1 + (size_t)l * IN_) : (u1 + (size_t)(l - 32) * IN_);
    float acc = (l < 32) ? b1[l] : c1[l - 32];
    #pragma unroll 8
    for (int i = 0; i < IN_; i += 4) {
        float4 w = *reinterpret_cast<const float4*>(wrow + i);
        acc += w.x * xs[i] + w.y * xs[i + 1] + w.z * xs[i + 2] + w.w * xs[i + 3];
    }
    if (l < 32) hw_out[(size_t)t * HID_ + l] = acc;
    else        hb[l - 32] = acc;
    __syncthreads();

    // bvec + LayerNorm over OUT=256 (4 values per thread)
    float bv[4];
    #pragma unroll
    for (int r = 0; r < 4; ++r) {
        const int o = l * 4 + r;
        const float* urow = u2 + (size_t)o * HID_;
        float a = c2[o];
        #pragma unroll
        for (int h = 0; h < HID_; h += 4) {
            float4 u = *reinterpret_cast<const float4*>(urow + h);
            a += u.x * hb[h] + u.y * hb[h + 1] + u.z * hb[h + 2] + u.w * hb[h + 3];
        }
        bv[r] = a;
    }
    float s = bv[0] + bv[1] + bv[2] + bv[3];
    float q = bv[0] * bv[0] + bv[1] * bv[1] + bv[2] * bv[2] + bv[3] * bv[3];
    #pragma unroll
    for (int off = 32; off > 0; off >>= 1) {
        s += __shfl_xor(s, off);
        q += __shfl_xor(q, off);
    }
    const float mu  = s * (1.0f / OUT_);
    const float var = q * (1.0f / OUT_) - mu * mu;
    const float inv = rsqrtf(var + EPS);
    #pragma unroll
    for (int r = 0; r < 4; ++r)
        bln_out[(size_t)t * OUT_ + l * 4 + r] = (bv[r] - mu) * inv;
}

// ---------------------------------------------------------------------------
// Kernel B: block = (o, chunk of 128 tokens), 256 threads = 4 waves.
// W2[o] (256 i x 32 h) staged in LDS as [h/4][i][4] (16B-aligned float4 rows,
// lanes read consecutive i -> contiguous -> conflict-free).
// Each wave processes token PAIRS (each LDS float4 read feeds 8 FMAs).
// Fused LN + dot:  y = inv*(dot_wx - mu*sum_x) + b_ln  via a 4-value
// butterfly reduction per token (no block barriers in the loop).
// ---------------------------------------------------------------------------
constexpr int TOK_PER_WG = 128;

__global__ __launch_bounds__(256)
void kb_main(const float* __restrict__ x,
             const float* __restrict__ w2, const float* __restrict__ b2,
             const float* __restrict__ hw, const float* __restrict__ bln,
             float* __restrict__ y)
{
    const int o     = blockIdx.x;   // 0..255
    const int chunk = blockIdx.y;   // 0..15
    const int tid   = threadIdx.x;  // 0..255
    const int lane  = tid & 63;
    const int wave  = tid >> 6;

    __shared__ float W2s[8][IN_][4];  // [h4][i][h%4]
    __shared__ float b2s[IN_];

    // stage W2[o] + b2[o]: thread tid owns i = tid (32 consecutive floats)
    {
        const float4* src = reinterpret_cast<const float4*>(
            w2 + ((size_t)o * IN_ + tid) * HID_);
        #pragma unroll
        for (int h4 = 0; h4 < 8; ++h4) {
            float4 v = src[h4];
            W2s[h4][tid][0] = v.x; W2s[h4][tid][1] = v.y;
            W2s[h4][tid][2] = v.z; W2s[h4][tid][3] = v.w;
        }
        b2s[tid] = b2[(size_t)o * IN_ + tid];
    }
    __syncthreads();

    const int tbase = chunk * TOK_PER_WG + wave * 2;

    for (int p = 0; p < TOK_PER_WG / 8; ++p) {  // 16 pairs per wave
        const int t0 = tbase + p * 8;
        const int t1 = t0 + 1;

        // hw rows (wave-uniform address -> broadcast load, L1-resident)
        float4 h0[8], h1[8];
        const float4* hp0 = reinterpret_cast<const float4*>(hw + (size_t)t0 * HID_);
        const float4* hp1 = reinterpret_cast<const float4*>(hw + (size_t)t1 * HID_);
        #pragma unroll
        for (int k = 0; k < 8; ++k) { h0[k] = hp0[k]; h1[k] = hp1[k]; }

        float s0 = 0, q0 = 0, d0 = 0, sx0 = 0;
        float s1 = 0, q1 = 0, d1 = 0, sx1 = 0;

        #pragma unroll
        for (int ir = 0; ir < 4; ++ir) {
            const int i = ir * 64 + lane;
            const float xv0 = x[(size_t)t0 * IN_ + i];
            const float xv1 = x[(size_t)t1 * IN_ + i];
            float w0 = b2s[i];
            float w1v = w0;
            #pragma unroll
            for (int h4 = 0; h4 < 8; ++h4) {
                const float4 c = *reinterpret_cast<const float4*>(&W2s[h4][i][0]);
                w0  += c.x * h0[h4].x + c.y * h0[h4].y + c.z * h0[h4].z + c.w * h0[h4].w;
                w1v += c.x * h1[h4].x + c.y * h1[h4].y + c.z * h1[h4].z + c.w * h1[h4].w;
            }
            s0 += w0;  q0 += w0 * w0;   d0 += w0 * xv0;   sx0 += xv0;
            s1 += w1v; q1 += w1v * w1v; d1 += w1v * xv1;  sx1 += xv1;
        }

        // butterfly reduce 8 values across the wave
        #pragma unroll
        for (int off = 32; off > 0; off >>= 1) {
            s0 += __shfl_xor(s0, off);  q0 += __shfl_xor(q0, off);
            d0 += __shfl_xor(d0, off);  sx0 += __shfl_xor(sx0, off);
            s1 += __shfl_xor(s1, off);  q1 += __shfl_xor(q1, off);
            d1 += __shfl_xor(d1, off);  sx1 += __shfl_xor(sx1, off);
        }

        if (lane == 0) {
            const float mu  = s0 * (1.0f / IN_);
            const float var = q0 * (1.0f / IN_) - mu * mu;
            const float inv = rsqrtf(var + EPS);
            y[(size_t)t0 * OUT_ + o] = inv * (d0 - mu * sx0) + bln[(size_t)t0 * OUT_ + o];
        } else if (lane == 1) {
            const float mu  = s1 * (1.0f / IN_);
            const float var = q1 * (1.0f / IN_) - mu * mu;
            const float inv = rsqrtf(var + EPS);
            y[(size_t)t1 * OUT_ + o] = inv * (d1 - mu * sx1) + bln[(size_t)t1 * OUT_ + o];
        }
    }
}

// ---------------------------------------------------------------------------
extern "C" void kernel_launch(void* const* d_in, const int* in_sizes, int n_in,
                              void* d_out, int out_size, void* d_ws, size_t ws_size,
                              hipStream_t stream)
{
    const float* x  = (const float*)d_in[0];
    const float* w1 = (const float*)d_in[1];
    const float* b1 = (const float*)d_in[2];
    const float* w2 = (const float*)d_in[3];
    const float* b2 = (const float*)d_in[4];
    const float* u1 = (const float*)d_in[5];
    const float* c1 = (const float*)d_in[6];
    const float* u2 = (const float*)d_in[7];
    const float* c2 = (const float*)d_in[8];
    float* y = (float*)d_out;

    float* hw_ws  = (float*)d_ws;                        // [2048,32]
    float* bln_ws = (float*)((char*)d_ws + (size_t)T_ * HID_ * sizeof(float)); // [2048,256]

    ka_hw_bias<<<T_, 64, 0, stream>>>(x, w1, b1, u1, c1, u2, c2, hw_ws, bln_ws);

    dim3 gridB(OUT_, T_ / TOK_PER_WG);  // (256, 16)
    kb_main<<<gridB, 256, 0, stream>>>(x, w2, b2, hw_ws, bln_ws, y);
}

// Round 2
// 99.042 us; speedup vs baseline: 5.0896x; 5.0896x over previous
//
#include <hip/hip_runtime.h>
#include <hip/hip_bf16.h>
#include <math.h>
#include <stdint.h>

#define EPS 1e-5f

constexpr int T_   = 2048;  // 4*512 tokens
constexpr int IN_  = 256;
constexpr int OUT_ = 256;
constexpr int HID_ = 32;
constexpr int XP   = 260;   // padded x row length (bf16 elems): 520 B rows -> conflict-free epilogue reads
constexpr int WP   = 40;    // padded w2 row length (bf16 elems): 80 B rows -> conflict-free b128 B-frag reads

typedef __attribute__((ext_vector_type(8))) short  short8;   // 8 bf16 (guide: frag_ab)
typedef __attribute__((ext_vector_type(4))) float  f32x4;    // MFMA C/D

static __device__ inline unsigned short f2b(float f) {
    __hip_bfloat16 h = __float2bfloat16(f);
    return *reinterpret_cast<unsigned short*>(&h);
}
static __device__ inline float b2f(unsigned short u) {
    union { unsigned int i; float f; } x; x.i = ((unsigned int)u) << 16; return x.f;
}

// async global->LDS staging: linear LDS dest (wave-uniform base + lane*16)
typedef const __attribute__((address_space(1))) uint32_t gas_u32;
typedef __attribute__((address_space(3))) uint32_t las_u32;
static __device__ inline void stage(void* l, const void* gp, int bytes, int lane, int wave) {
    for (int off = wave * 1024; off < bytes; off += 4096) {
        if (off + lane * 16 < bytes)
            __builtin_amdgcn_global_load_lds(
                (gas_u32*)((const char*)gp + off + lane * 16),
                (las_u32*)((char*)l + off), 16, 0, 0);
    }
}

// ---------------------------------------------------------------------------
// k_conv_w2: w2 fp32 [65536,32] -> bf16 padded rows [65536, WP=40] (80 B rows)
// ---------------------------------------------------------------------------
__global__ __launch_bounds__(256)
void k_conv_w2(const float* __restrict__ w2, unsigned short* __restrict__ w2p)
{
    const int gid  = blockIdx.x * 256 + threadIdx.x;   // 0..131071
    const int row  = gid >> 1;
    const int half = gid & 1;
    const float4* src = reinterpret_cast<const float4*>(w2 + (size_t)row * HID_ + half * 16);
    float4 v[4];
    #pragma unroll
    for (int k = 0; k < 4; ++k) v[k] = src[k];
    const float* vf = reinterpret_cast<const float*>(v);
    unsigned int pk[8];
    #pragma unroll
    for (int k = 0; k < 8; ++k)
        pk[k] = (unsigned int)f2b(vf[2 * k]) | ((unsigned int)f2b(vf[2 * k + 1]) << 16);
    uint4* dst = reinterpret_cast<uint4*>(w2p + (size_t)row * WP + half * 16);
    dst[0] = make_uint4(pk[0], pk[1], pk[2], pk[3]);
    dst[1] = make_uint4(pk[4], pk[5], pk[6], pk[7]);
}

// ---------------------------------------------------------------------------
// ka: per token t: hw (bf16 out), sx = sum(x), xpad bf16, hb -> bvec -> LN -> bln
// ---------------------------------------------------------------------------
__global__ __launch_bounds__(64)
void ka_hw_bias(const float* __restrict__ x,
                const float* __restrict__ w1, const float* __restrict__ b1,
                const float* __restrict__ u1, const float* __restrict__ c1,
                const float* __restrict__ u2, const float* __restrict__ c2,
                unsigned short* __restrict__ hwbf_out,  // [T,32] bf16
                unsigned short* __restrict__ xp_out,    // [T,XP] bf16 (padded rows)
                float* __restrict__ sx_out,             // [T]
                float* __restrict__ bln_out)            // [T,256]
{
    const int t = blockIdx.x;
    const int l = threadIdx.x;

    __shared__ float xs[IN_];
    __shared__ float hb[HID_];

    float4 x4 = reinterpret_cast<const float4*>(x + (size_t)t * IN_)[l];
    reinterpret_cast<float4*>(xs)[l] = x4;

    // sx[t] = sum_i x[t,i]
    float s = x4.x + x4.y + x4.z + x4.w;
    #pragma unroll
    for (int off = 32; off > 0; off >>= 1) s += __shfl_xor(s, off);
    if (l == 0) sx_out[t] = s;

    // xpad bf16 row
    {
        ushort4 ux;
        ux.x = f2b(x4.x); ux.y = f2b(x4.y); ux.z = f2b(x4.z); ux.w = f2b(x4.w);
        *reinterpret_cast<ushort4*>(xp_out + (size_t)t * XP + l * 4) = ux;
    }
    __syncthreads();

    // hw (threads 0..31) / hb (threads 32..63)
    const float* wrow = (l < 32) ? (w1 + (size_t)l * IN_) : (u1 + (size_t)(l - 32) * IN_);
    float acc = (l < 32) ? b1[l] : c1[l - 32];
    #pragma unroll 8
    for (int i = 0; i < IN_; i += 4) {
        float4 w = *reinterpret_cast<const float4*>(wrow + i);
        acc += w.x * xs[i] + w.y * xs[i + 1] + w.z * xs[i + 2] + w.w * xs[i + 3];
    }
    if (l < 32) hwbf_out[(size_t)t * HID_ + l] = f2b(acc);
    else        hb[l - 32] = acc;
    __syncthreads();

    // bvec + LayerNorm over OUT=256 (4 values per thread)
    float bv[4];
    #pragma unroll
    for (int r = 0; r < 4; ++r) {
        const int o = l * 4 + r;
        const float* urow = u2 + (size_t)o * HID_;
        float a = c2[o];
        #pragma unroll
        for (int h = 0; h < HID_; h += 4) {
            float4 u = *reinterpret_cast<const float4*>(urow + h);
            a += u.x * hb[h] + u.y * hb[h + 1] + u.z * hb[h + 2] + u.w * hb[h + 3];
        }
        bv[r] = a;
    }
    float ss = bv[0] + bv[1] + bv[2] + bv[3];
    float qq = bv[0] * bv[0] + bv[1] * bv[1] + bv[2] * bv[2] + bv[3] * bv[3];
    #pragma unroll
    for (int off = 32; off > 0; off >>= 1) {
        ss += __shfl_xor(ss, off);
        qq += __shfl_xor(qq, off);
    }
    const float mu  = ss * (1.0f / OUT_);
    const float var = qq * (1.0f / OUT_) - mu * mu;
    const float inv = rsqrtf(var + EPS);
    #pragma unroll
    for (int r = 0; r < 4; ++r)
        bln_out[(size_t)t * OUT_ + l * 4 + r] = (bv[r] - mu) * inv;
}

// ---------------------------------------------------------------------------
// k_main: block = (chunk of 64 tokens, o). One MFMA K-step (K=HID=32).
//   wave w: C[t=w*16..+15, i=0..255] = mfma(hw_tile, w2[o] tile, C0=b2[o,i])
//   epilogue: sw=Σ_i C, qq=Σ_i C², dw=Σ_i C·x  -> fused LN -> y
// ---------------------------------------------------------------------------
__global__ __launch_bounds__(256, 2)
void k_main(const unsigned short* __restrict__ w2p,  // [65536, WP] bf16
            const float* __restrict__ b2,            // [65536] fp32
            const unsigned short* __restrict__ hwbf, // [T,32] bf16
            const unsigned short* __restrict__ xp,   // [T,XP] bf16
            const float* __restrict__ sx,            // [T]
            const float* __restrict__ bln,           // [T,256]
            float* __restrict__ y)                   // [T,256]
{
    __shared__ __align__(16) unsigned short xs_sh[64 * XP];   // 33280 B
    __shared__ __align__(16) unsigned short ws_sh[256 * WP];  // 20480 B
    __shared__ __align__(16) unsigned short hw_sh[64 * 32];   //  4096 B
    __shared__ __align__(16) float          b2_sh[256];       //  1024 B

    const int tid   = threadIdx.x;
    const int lane  = tid & 63;
    const int wave  = tid >> 6;
    const int chunk = blockIdx.x;   // 0..31
    const int o     = blockIdx.y;   // 0..255
    const int t0    = chunk * 64;

    stage(xs_sh, xp   + (size_t)t0 * XP,        64 * XP * 2,  lane, wave);
    stage(ws_sh, w2p  + (size_t)o * IN_ * WP,   256 * WP * 2, lane, wave);
    stage(hw_sh, hwbf + (size_t)t0 * HID_,      64 * 32 * 2,  lane, wave);
    stage(b2_sh, b2   + (size_t)o * IN_,        256 * 4,      lane, wave);
    __syncthreads();

    const int c = lane & 15;    // A row / B col / D col within fragment
    const int g = lane >> 4;    // k-chunk for A/B; row-group for D

    // A-frag: hw rows of this wave's 16 tokens; lane: row=c, k = g*8..g*8+7
    short8 a = *reinterpret_cast<const short8*>(&hw_sh[(wave * 16 + c) * 32 + g * 8]);

    f32x4 acc[16];
    #pragma unroll
    for (int ni = 0; ni < 16; ++ni) {
        // B-frag: col i = ni*16+c, k = g*8..g*8+7  (w2B row-major padded)
        short8 b = *reinterpret_cast<const short8*>(&ws_sh[(ni * 16 + c) * WP + g * 8]);
        float bi = b2_sh[ni * 16 + c];
        f32x4 cin = {bi, bi, bi, bi};
        acc[ni] = __builtin_amdgcn_mfma_f32_16x16x32_bf16(a, b, cin, 0, 0, 0);
    }

    // epilogue: per lane, D element (row = g*4+j, col = ni*16+c)
    float sw_[4] = {0, 0, 0, 0}, qq_[4] = {0, 0, 0, 0}, dw_[4] = {0, 0, 0, 0};
    #pragma unroll
    for (int ni = 0; ni < 16; ++ni) {
        #pragma unroll
        for (int j = 0; j < 4; ++j) {
            float v  = acc[ni][j];
            float xv = b2f(xs_sh[(wave * 16 + g * 4 + j) * XP + ni * 16 + c]);
            sw_[j] += v;
            qq_[j] += v * v;
            dw_[j] += v * xv;
        }
    }
    // reduce over the 16 columns held across lanes (lane bits 0..3)
    #pragma unroll
    for (int j = 0; j < 4; ++j) {
        #pragma unroll
        for (int off = 1; off <= 8; off <<= 1) {
            sw_[j] += __shfl_xor(sw_[j], off);
            qq_[j] += __shfl_xor(qq_[j], off);
            dw_[j] += __shfl_xor(dw_[j], off);
        }
    }
    if (c == 0) {
        #pragma unroll
        for (int j = 0; j < 4; ++j) {
            const int t   = t0 + wave * 16 + g * 4 + j;
            const float mu  = sw_[j] * (1.0f / IN_);
            const float var = qq_[j] * (1.0f / IN_) - mu * mu;
            const float inv = rsqrtf(var + EPS);
            y[(size_t)t * OUT_ + o] = inv * (dw_[j] - mu * sx[t]) + bln[(size_t)t * OUT_ + o];
        }
    }
}

// ---------------------------------------------------------------------------
extern "C" void kernel_launch(void* const* d_in, const int* in_sizes, int n_in,
                              void* d_out, int out_size, void* d_ws, size_t ws_size,
                              hipStream_t stream)
{
    const float* x  = (const float*)d_in[0];
    const float* w1 = (const float*)d_in[1];
    const float* b1 = (const float*)d_in[2];
    const float* w2 = (const float*)d_in[3];
    const float* b2 = (const float*)d_in[4];
    const float* u1 = (const float*)d_in[5];
    const float* c1 = (const float*)d_in[6];
    const float* u2 = (const float*)d_in[7];
    const float* c2 = (const float*)d_in[8];
    float* y = (float*)d_out;

    // workspace layout (all 16B aligned)
    char* ws = (char*)d_ws;
    unsigned short* w2p  = (unsigned short*)(ws);                 // 65536*80  = 5,242,880 B
    unsigned short* xpad = (unsigned short*)(ws + 5242880);       // 2048*520  = 1,064,960 B
    unsigned short* hwbf = (unsigned short*)(ws + 6307840);       // 2048*64   =   131,072 B
    float*          sxp  = (float*)         (ws + 6438912);       // 2048*4    =     8,192 B
    float*          blnp = (float*)         (ws + 6447104);       // 2048*1024 = 2,097,152 B -> 8,544,256 total

    k_conv_w2<<<512, 256, 0, stream>>>(w2, w2p);
    ka_hw_bias<<<T_, 64, 0, stream>>>(x, w1, b1, u1, c1, u2, c2, hwbf, xpad, sxp, blnp);

    dim3 gridM(32, 256);  // x = token chunk (fast) -> XCD neighbors share w2[o] in L2
    k_main<<<gridM, 256, 0, stream>>>(w2p, b2, hwbf, xpad, sxp, blnp, y);
}

// Round 3
// 87.622 us; speedup vs baseline: 5.7529x; 1.1303x over previous
//
#include <hip/hip_runtime.h>
#include <hip/hip_bf16.h>
#include <stdint.h>

#define EPS 1e-5f

constexpr int T_   = 2048;
constexpr int IN_  = 256;
constexpr int HID_ = 32;
constexpr int XP   = 264;    // x row pad (u16): 528 B rows
constexpr int HP   = 40;     // hw row pad (u16): 80 B rows
constexpr int KB_  = 9728;   // Bfull row length (u16)
// Bfull k-map: [0,8192) W2 flat (k=i*32+h); [8192,8448) b2; [8448,9472) Q2;
// [9472,9504) 2*P2; [9504] qb2; [9536,9568) S2; [9568] sb2; rest zeros.

typedef __attribute__((ext_vector_type(8))) short short8;
typedef __attribute__((ext_vector_type(4))) float f32x4;

union AB { unsigned int u[4]; short8 s8; };

typedef const __attribute__((address_space(1))) uint32_t gas_u32;
typedef __attribute__((address_space(3))) uint32_t las_u32;

static __device__ __forceinline__ void gll16(const void* src, void* dst) {
    __builtin_amdgcn_global_load_lds((gas_u32*)src, (las_u32*)dst, 16, 0, 0);
}
static __device__ __forceinline__ unsigned short f2b(float f) {
    __hip_bfloat16 h = __float2bfloat16(f);
    return *reinterpret_cast<unsigned short*>(&h);
}
static __device__ __forceinline__ unsigned int cvtpk(float lo, float hi) {
    unsigned int r;
    asm("v_cvt_pk_bf16_f32 %0, %1, %2" : "=v"(r) : "v"(lo), "v"(hi));
    return r;
}

// ---------------------------------------------------------------------------
// k_prep_b: per o — W2 rows -> bf16 flat, b2 -> bf16, P2/S2/sb2/qb2 + zeros
// ---------------------------------------------------------------------------
__global__ __launch_bounds__(256)
void k_prep_b(const float* __restrict__ w2, const float* __restrict__ b2,
              unsigned short* __restrict__ Bf)
{
    __shared__ __align__(16) float w2s[256 * 32];
    __shared__ __align__(16) float b2s[256];
    __shared__ float pP[8][32], pS[8][32], pB[8], pQ[8];
    const int tid = threadIdx.x, lane = tid & 63, wave = tid >> 6;
    const int o = blockIdx.x;
    const float* w2o = w2 + (size_t)o * 8192;

    #pragma unroll
    for (int q = 0; q < 8; ++q) {
        int I = wave * 8 + q;
        gll16(w2o + I * 256 + lane * 4, w2s + I * 256);
    }
    if (wave == 0) gll16(b2 + (size_t)o * 256 + lane * 4, b2s);
    asm volatile("s_waitcnt vmcnt(0)" ::: "memory");
    __syncthreads();

    unsigned short* row = Bf + (size_t)o * KB_;

    { // W2 flat bf16 [0,8192)
        const float* src = w2s + tid * 32;
        unsigned int pk[16];
        #pragma unroll
        for (int d = 0; d < 16; ++d) pk[d] = cvtpk(src[2 * d], src[2 * d + 1]);
        uint4* dst = (uint4*)(row + tid * 32);
        dst[0] = make_uint4(pk[0], pk[1], pk[2], pk[3]);
        dst[1] = make_uint4(pk[4], pk[5], pk[6], pk[7]);
        dst[2] = make_uint4(pk[8], pk[9], pk[10], pk[11]);
        dst[3] = make_uint4(pk[12], pk[13], pk[14], pk[15]);
    }
    row[8192 + tid] = f2b(b2s[tid]);   // b2 [8192,8448)

    { // partial P2/S2 + b2 sums
        int h = tid & 31, s = tid >> 5;
        float pa = 0.f, sa = 0.f;
        for (int i = s * 32; i < s * 32 + 32; ++i) {
            float wv = w2s[i * 32 + h];
            pa += wv * b2s[i];
            sa += wv;
        }
        pP[s][h] = pa; pS[s][h] = sa;
        if (h == 0) {
            float sb = 0.f, qb = 0.f;
            for (int i = s * 32; i < s * 32 + 32; ++i) {
                float bv = b2s[i]; sb += bv; qb += bv * bv;
            }
            pB[s] = sb; pQ[s] = qb;
        }
    }
    __syncthreads();
    if (tid < 32) {
        float p = 0.f, sv = 0.f;
        #pragma unroll
        for (int s2 = 0; s2 < 8; ++s2) { p += pP[s2][tid]; sv += pS[s2][tid]; }
        row[9472 + tid] = f2b(2.0f * p);
        row[9536 + tid] = f2b(sv);
    } else if (tid == 32) {
        float sb = 0.f;
        #pragma unroll
        for (int s2 = 0; s2 < 8; ++s2) sb += pB[s2];
        row[9568] = f2b(sb);
    } else if (tid == 33) {
        float qb = 0.f;
        #pragma unroll
        for (int s2 = 0; s2 < 8; ++s2) qb += pQ[s2];
        row[9504] = f2b(qb);
    }
    // zeros
    if (tid < 31) row[9505 + tid] = 0;
    {
        int z = tid - 31; if (z >= 0 && z < 31) row[9569 + z] = 0;
    }
    {
        int z = tid - 62; if (z >= 0 && z < 128) row[9600 + z] = 0;
    }
}

// ---------------------------------------------------------------------------
// k_gram: per o — Q2 = W2[o]^T W2[o] via MFMA (one wave), writes [8448,9472)
// ---------------------------------------------------------------------------
__global__ __launch_bounds__(64)
void k_gram(const float* __restrict__ w2, unsigned short* __restrict__ Bf)
{
    const int lane = threadIdx.x, c = lane & 15, g = lane >> 4;
    const int o = blockIdx.x;
    const float* w2o = w2 + (size_t)o * 8192;
    f32x4 acc00 = {0,0,0,0}, acc01 = {0,0,0,0}, acc10 = {0,0,0,0}, acc11 = {0,0,0,0};
    #pragma unroll
    for (int s = 0; s < 8; ++s) {
        AB af[2];
        #pragma unroll
        for (int mt = 0; mt < 2; ++mt) {
            float wv[8];
            #pragma unroll
            for (int v = 0; v < 8; ++v)
                wv[v] = w2o[(size_t)(s * 32 + g * 8 + v) * 32 + mt * 16 + c];
            #pragma unroll
            for (int d = 0; d < 4; ++d) af[mt].u[d] = cvtpk(wv[2 * d], wv[2 * d + 1]);
        }
        acc00 = __builtin_amdgcn_mfma_f32_16x16x32_bf16(af[0].s8, af[0].s8, acc00, 0, 0, 0);
        acc01 = __builtin_amdgcn_mfma_f32_16x16x32_bf16(af[0].s8, af[1].s8, acc01, 0, 0, 0);
        acc10 = __builtin_amdgcn_mfma_f32_16x16x32_bf16(af[1].s8, af[0].s8, acc10, 0, 0, 0);
        acc11 = __builtin_amdgcn_mfma_f32_16x16x32_bf16(af[1].s8, af[1].s8, acc11, 0, 0, 0);
    }
    unsigned short* row = Bf + (size_t)o * KB_ + 8448;
    #pragma unroll
    for (int j = 0; j < 4; ++j) {
        row[(0  + g * 4 + j) * 32 + 0  + c] = f2b(acc00[j]);
        row[(0  + g * 4 + j) * 32 + 16 + c] = f2b(acc01[j]);
        row[(16 + g * 4 + j) * 32 + 0  + c] = f2b(acc10[j]);
        row[(16 + g * 4 + j) * 32 + 16 + c] = f2b(acc11[j]);
    }
}

// ---------------------------------------------------------------------------
// ka: per token — hw (bf16, padded), xpad bf16, sx, bln (LN of bias path)
// ---------------------------------------------------------------------------
__global__ __launch_bounds__(64)
void ka_hw_bias(const float* __restrict__ x,
                const float* __restrict__ w1, const float* __restrict__ b1,
                const float* __restrict__ u1, const float* __restrict__ c1,
                const float* __restrict__ u2, const float* __restrict__ c2,
                unsigned short* __restrict__ hwbf_out,  // [T,HP]
                unsigned short* __restrict__ xp_out,    // [T,XP]
                float* __restrict__ sx_out,             // [T]
                float* __restrict__ bln_out)            // [T,256]
{
    const int t = blockIdx.x;
    const int l = threadIdx.x;

    __shared__ float xs[IN_];
    __shared__ float hb[HID_];

    float4 x4 = reinterpret_cast<const float4*>(x + (size_t)t * IN_)[l];
    reinterpret_cast<float4*>(xs)[l] = x4;

    float s = x4.x + x4.y + x4.z + x4.w;
    #pragma unroll
    for (int off = 32; off > 0; off >>= 1) s += __shfl_xor(s, off);
    if (l == 0) sx_out[t] = s;

    {
        ushort4 ux;
        ux.x = f2b(x4.x); ux.y = f2b(x4.y); ux.z = f2b(x4.z); ux.w = f2b(x4.w);
        *reinterpret_cast<ushort4*>(xp_out + (size_t)t * XP + l * 4) = ux;
    }
    __syncthreads();

    const float* wrow = (l < 32) ? (w1 + (size_t)l * IN_) : (u1 + (size_t)(l - 32) * IN_);
    float acc = (l < 32) ? b1[l] : c1[l - 32];
    #pragma unroll 8
    for (int i = 0; i < IN_; i += 4) {
        float4 w = *reinterpret_cast<const float4*>(wrow + i);
        acc += w.x * xs[i] + w.y * xs[i + 1] + w.z * xs[i + 2] + w.w * xs[i + 3];
    }
    if (l < 32) hwbf_out[(size_t)t * HP + l] = f2b(acc);
    else        hb[l - 32] = acc;
    __syncthreads();

    float bv[4];
    #pragma unroll
    for (int r = 0; r < 4; ++r) {
        const int o = l * 4 + r;
        const float* urow = u2 + (size_t)o * HID_;
        float a = c2[o];
        #pragma unroll
        for (int h = 0; h < HID_; h += 4) {
            float4 u = *reinterpret_cast<const float4*>(urow + h);
            a += u.x * hb[h] + u.y * hb[h + 1] + u.z * hb[h + 2] + u.w * hb[h + 3];
        }
        bv[r] = a;
    }
    float ss = bv[0] + bv[1] + bv[2] + bv[3];
    float qq = bv[0] * bv[0] + bv[1] * bv[1] + bv[2] * bv[2] + bv[3] * bv[3];
    #pragma unroll
    for (int off = 32; off > 0; off >>= 1) {
        ss += __shfl_xor(ss, off);
        qq += __shfl_xor(qq, off);
    }
    const float mu  = ss * (1.0f / 256.f);
    const float var = qq * (1.0f / 256.f) - mu * mu;
    const float inv = rsqrtf(var + EPS);
    #pragma unroll
    for (int r = 0; r < 4; ++r)
        bln_out[(size_t)t * 256 + l * 4 + r] = (bv[r] - mu) * inv;
}

// ---------------------------------------------------------------------------
// k_main: block = (o-tile 32, t-tile 64); 4 waves = 2(t) x 2(o);
// wave = 32t x 16o; K-loop of 75 chunks (128 k each), dw/qq/sw accumulators.
// ---------------------------------------------------------------------------
__global__ __launch_bounds__(256)
void k_main(const unsigned short* __restrict__ Bf,
            const unsigned short* __restrict__ xpad,
            const unsigned short* __restrict__ hwbf,
            const float* __restrict__ sx,
            const float* __restrict__ bln,
            float* __restrict__ y)
{
    __shared__ __align__(16) unsigned short Bb[2][4096];      // 2 x 8 KB
    __shared__ __align__(16) unsigned short x_sh[64 * XP];    // 33792 B
    __shared__ __align__(16) unsigned short hw_sh[64 * HP];   // 5120 B

    const int tid  = threadIdx.x, lane = tid & 63, wave = tid >> 6;
    const int c    = lane & 15, g = lane >> 4;
    const int wr   = wave >> 1, wc = wave & 1;
    const int otile = blockIdx.x;          // 0..7
    const int t0    = blockIdx.y * 64;     // 0..31 tiles
    const int o32   = wc * 16 + c;
    const int bkey  = o32 & 7;
    const int brow  = o32 * 128;

    // ---- prologue staging ----
    for (int I = wave; I < 33; I += 4)
        gll16(xpad + (size_t)t0 * XP + I * 512 + lane * 8, x_sh + I * 512);
    for (int I = wave; I < 5; I += 4)
        gll16(hwbf + (size_t)t0 * HP + I * 512 + lane * 8, hw_sh + I * 512);

    auto stageB = [&](int cc, int nb) {
        #pragma unroll
        for (int q = 0; q < 2; ++q) {
            int I = wave * 2 + q;
            int r = I * 4 + (lane >> 4);
            int su = (lane & 15) ^ (r & 7);
            gll16(Bf + (size_t)(otile * 32 + r) * KB_ + cc * 128 + su * 8,
                  &Bb[nb][I * 512]);
        }
    };
    stageB(0, 0);
    asm volatile("s_waitcnt vmcnt(0)" ::: "memory");
    __builtin_amdgcn_s_barrier();

    // ---- hw fragments (constant over K) ----
    const int xrow0 = (wr * 32 + c) * XP,      xrow1 = xrow0 + 16 * XP;
    const int hrow0 = (wr * 32 + c) * HP,      hrow1 = hrow0 + 16 * HP;
    AB hp0, hp1;
    {
        uint4 v0 = *(const uint4*)&hw_sh[hrow0 + g * 8];
        uint4 v1 = *(const uint4*)&hw_sh[hrow1 + g * 8];
        hp0.u[0] = v0.x; hp0.u[1] = v0.y; hp0.u[2] = v0.z; hp0.u[3] = v0.w;
        hp1.u[0] = v1.x; hp1.u[1] = v1.y; hp1.u[2] = v1.z; hp1.u[3] = v1.w;
    }
    float hwf0[8], hwf1[8];
    #pragma unroll
    for (int d = 0; d < 4; ++d) {
        hwf0[2 * d]     = __uint_as_float(hp0.u[d] << 16);
        hwf0[2 * d + 1] = __uint_as_float(hp0.u[d] & 0xFFFF0000u);
        hwf1[2 * d]     = __uint_as_float(hp1.u[d] << 16);
        hwf1[2 * d + 1] = __uint_as_float(hp1.u[d] & 0xFFFF0000u);
    }

    f32x4 dw0 = {0,0,0,0}, dw1 = {0,0,0,0};
    f32x4 qq0 = {0,0,0,0}, qq1 = {0,0,0,0};
    f32x4 sw0 = {0,0,0,0}, sw1 = {0,0,0,0};

    int buf = 0;
    // ---- MODE X: chunks 0..63 (A = x-scalar * hw-frag) ----
    for (int cc = 0; cc < 64; ++cc) {
        stageB(cc + 1, buf ^ 1);
        uint2 xq0 = *(const uint2*)&x_sh[xrow0 + cc * 4];
        uint2 xq1 = *(const uint2*)&x_sh[xrow1 + cc * 4];
        asm volatile("s_waitcnt vmcnt(2)" ::: "memory");
        __builtin_amdgcn_s_barrier();
        const unsigned short* bbase = &Bb[buf][brow];
        #pragma unroll
        for (int u = 0; u < 4; ++u) {
            unsigned int d0 = (u >> 1) ? xq0.y : xq0.x;
            unsigned int d1 = (u >> 1) ? xq1.y : xq1.x;
            float xv0 = __uint_as_float((u & 1) ? (d0 & 0xFFFF0000u) : (d0 << 16));
            float xv1 = __uint_as_float((u & 1) ? (d1 & 0xFFFF0000u) : (d1 << 16));
            AB a0, a1;
            #pragma unroll
            for (int d = 0; d < 4; ++d) {
                a0.u[d] = cvtpk(xv0 * hwf0[2 * d], xv0 * hwf0[2 * d + 1]);
                a1.u[d] = cvtpk(xv1 * hwf1[2 * d], xv1 * hwf1[2 * d + 1]);
            }
            short8 b = *(const short8*)&bbase[((u * 4 + g) ^ bkey) * 8];
            dw0 = __builtin_amdgcn_mfma_f32_16x16x32_bf16(a0.s8, b, dw0, 0, 0, 0);
            dw1 = __builtin_amdgcn_mfma_f32_16x16x32_bf16(a1.s8, b, dw1, 0, 0, 0);
        }
        __builtin_amdgcn_s_barrier();
        buf ^= 1;
    }
    // ---- MODE DX: chunks 64..65 (A = x-frag direct, B = b2) ----
    for (int cc = 64; cc < 66; ++cc) {
        stageB(cc + 1, buf ^ 1);
        asm volatile("s_waitcnt vmcnt(2)" ::: "memory");
        __builtin_amdgcn_s_barrier();
        const unsigned short* bbase = &Bb[buf][brow];
        #pragma unroll
        for (int u = 0; u < 4; ++u) {
            AB a0, a1;
            a0.s8 = *(const short8*)&x_sh[xrow0 + (cc - 64) * 128 + u * 32 + g * 8];
            a1.s8 = *(const short8*)&x_sh[xrow1 + (cc - 64) * 128 + u * 32 + g * 8];
            short8 b = *(const short8*)&bbase[((u * 4 + g) ^ bkey) * 8];
            dw0 = __builtin_amdgcn_mfma_f32_16x16x32_bf16(a0.s8, b, dw0, 0, 0, 0);
            dw1 = __builtin_amdgcn_mfma_f32_16x16x32_bf16(a1.s8, b, dw1, 0, 0, 0);
        }
        __builtin_amdgcn_s_barrier();
        buf ^= 1;
    }
    // ---- MODE HW: chunks 66..73 (A = hw-scalar * hw-frag, B = Q2) ----
    for (int cc = 66; cc < 74; ++cc) {
        stageB(cc + 1, buf ^ 1);
        uint2 hq0 = *(const uint2*)&hw_sh[hrow0 + (cc - 66) * 4];
        uint2 hq1 = *(const uint2*)&hw_sh[hrow1 + (cc - 66) * 4];
        asm volatile("s_waitcnt vmcnt(2)" ::: "memory");
        __builtin_amdgcn_s_barrier();
        const unsigned short* bbase = &Bb[buf][brow];
        #pragma unroll
        for (int u = 0; u < 4; ++u) {
            unsigned int d0 = (u >> 1) ? hq0.y : hq0.x;
            unsigned int d1 = (u >> 1) ? hq1.y : hq1.x;
            float hv0 = __uint_as_float((u & 1) ? (d0 & 0xFFFF0000u) : (d0 << 16));
            float hv1 = __uint_as_float((u & 1) ? (d1 & 0xFFFF0000u) : (d1 << 16));
            AB a0, a1;
            #pragma unroll
            for (int d = 0; d < 4; ++d) {
                a0.u[d] = cvtpk(hv0 * hwf0[2 * d], hv0 * hwf0[2 * d + 1]);
                a1.u[d] = cvtpk(hv1 * hwf1[2 * d], hv1 * hwf1[2 * d + 1]);
            }
            short8 b = *(const short8*)&bbase[((u * 4 + g) ^ bkey) * 8];
            qq0 = __builtin_amdgcn_mfma_f32_16x16x32_bf16(a0.s8, b, qq0, 0, 0, 0);
            qq1 = __builtin_amdgcn_mfma_f32_16x16x32_bf16(a1.s8, b, qq1, 0, 0, 0);
        }
        __builtin_amdgcn_s_barrier();
        buf ^= 1;
    }
    // ---- chunk 74: P2 | qb2 | S2 | sb2 ----
    {
        asm volatile("s_waitcnt vmcnt(0)" ::: "memory");
        __builtin_amdgcn_s_barrier();
        const unsigned short* bbase = &Bb[buf][brow];
        AB e0;
        e0.u[0] = (g == 0) ? 0x3F80u : 0u;
        e0.u[1] = 0; e0.u[2] = 0; e0.u[3] = 0;

        short8 b0 = *(const short8*)&bbase[((0 * 4 + g) ^ bkey) * 8];
        qq0 = __builtin_amdgcn_mfma_f32_16x16x32_bf16(hp0.s8, b0, qq0, 0, 0, 0);
        qq1 = __builtin_amdgcn_mfma_f32_16x16x32_bf16(hp1.s8, b0, qq1, 0, 0, 0);
        short8 b1 = *(const short8*)&bbase[((1 * 4 + g) ^ bkey) * 8];
        qq0 = __builtin_amdgcn_mfma_f32_16x16x32_bf16(e0.s8, b1, qq0, 0, 0, 0);
        qq1 = __builtin_amdgcn_mfma_f32_16x16x32_bf16(e0.s8, b1, qq1, 0, 0, 0);
        short8 b2v = *(const short8*)&bbase[((2 * 4 + g) ^ bkey) * 8];
        sw0 = __builtin_amdgcn_mfma_f32_16x16x32_bf16(hp0.s8, b2v, sw0, 0, 0, 0);
        sw1 = __builtin_amdgcn_mfma_f32_16x16x32_bf16(hp1.s8, b2v, sw1, 0, 0, 0);
        short8 b3 = *(const short8*)&bbase[((3 * 4 + g) ^ bkey) * 8];
        sw0 = __builtin_amdgcn_mfma_f32_16x16x32_bf16(e0.s8, b3, sw0, 0, 0, 0);
        sw1 = __builtin_amdgcn_mfma_f32_16x16x32_bf16(e0.s8, b3, sw1, 0, 0, 0);
    }

    // ---- epilogue: fused LN + y ----
    const int o = otile * 32 + o32;
    #pragma unroll
    for (int j = 0; j < 4; ++j) {
        {
            int t = t0 + wr * 32 + g * 4 + j;
            float muv = sw0[j] * (1.f / 256.f);
            float varv = qq0[j] * (1.f / 256.f) - muv * muv;
            float inv = rsqrtf(varv + EPS);
            y[(size_t)t * 256 + o] = inv * (dw0[j] - muv * sx[t]) + bln[(size_t)t * 256 + o];
        }
        {
            int t = t0 + wr * 32 + 16 + g * 4 + j;
            float muv = sw1[j] * (1.f / 256.f);
            float varv = qq1[j] * (1.f / 256.f) - muv * muv;
            float inv = rsqrtf(varv + EPS);
            y[(size_t)t * 256 + o] = inv * (dw1[j] - muv * sx[t]) + bln[(size_t)t * 256 + o];
        }
    }
}

// ---------------------------------------------------------------------------
extern "C" void kernel_launch(void* const* d_in, const int* in_sizes, int n_in,
                              void* d_out, int out_size, void* d_ws, size_t ws_size,
                              hipStream_t stream)
{
    (void)in_sizes; (void)n_in; (void)out_size; (void)ws_size;
    const float* x  = (const float*)d_in[0];
    const float* w1 = (const float*)d_in[1];
    const float* b1 = (const float*)d_in[2];
    const float* w2 = (const float*)d_in[3];
    const float* b2 = (const float*)d_in[4];
    const float* u1 = (const float*)d_in[5];
    const float* c1 = (const float*)d_in[6];
    const float* u2 = (const float*)d_in[7];
    const float* c2 = (const float*)d_in[8];
    float* y = (float*)d_out;

    char* ws = (char*)d_ws;
    unsigned short* Bfull = (unsigned short*)(ws);                 // 256*9728*2 = 4,980,736
    unsigned short* xpad  = (unsigned short*)(ws + 4980736);       // 2048*264*2 = 1,081,344
    unsigned short* hwbf  = (unsigned short*)(ws + 6062080);       // 2048*40*2  =   163,840
    float*          sxp   = (float*)(ws + 6225920);                // 2048*4
    float*          blnp  = (float*)(ws + 6234112);                // 2048*256*4 -> 8,331,264 total

    k_prep_b<<<256, 256, 0, stream>>>(w2, b2, Bfull);
    k_gram<<<256, 64, 0, stream>>>(w2, Bfull);
    ka_hw_bias<<<T_, 64, 0, stream>>>(x, w1, b1, u1, c1, u2, c2, hwbf, xpad, sxp, blnp);

    dim3 gm(8, 32);   // x = o-tile (XCD-aligned), y = t-tile
    k_main<<<gm, 256, 0, stream>>>(Bfull, xpad, hwbf, sxp, blnp, y);
}

// Round 4
// 85.744 us; speedup vs baseline: 5.8789x; 1.0219x over previous
//
#include <hip/hip_runtime.h>
#include <hip/hip_bf16.h>
#include <stdint.h>

#define EPS 1e-5f

constexpr int T_   = 2048;
constexpr int IN_  = 256;
constexpr int HID_ = 32;
constexpr int XP   = 264;    // x row pad (u16)
constexpr int HP   = 40;     // hw row pad (u16)
constexpr int KB_  = 9728;   // Bfull row length (u16)
// Bfull k-map: [0,8192) W2 flat (k=i*32+h); [8192,8448) b2; [8448,9472) Q2;
// [9472,9504) 2*P2; [9504] qb2; [9536,9568) S2; [9568] sb2; rest zeros.

typedef __attribute__((ext_vector_type(8))) short short8;
typedef __attribute__((ext_vector_type(4))) float f32x4;

union AB { unsigned int u[4]; short8 s8; };

typedef const __attribute__((address_space(1))) uint32_t gas_u32;
typedef __attribute__((address_space(3))) uint32_t las_u32;

static __device__ __forceinline__ void gll16(const void* src, void* dst) {
    __builtin_amdgcn_global_load_lds((gas_u32*)src, (las_u32*)dst, 16, 0, 0);
}
static __device__ __forceinline__ unsigned short f2b(float f) {
    __hip_bfloat16 h = __float2bfloat16(f);
    return *reinterpret_cast<unsigned short*>(&h);
}
static __device__ __forceinline__ unsigned int cvtpk(float lo, float hi) {
    unsigned int r;
    asm("v_cvt_pk_bf16_f32 %0, %1, %2" : "=v"(r) : "v"(lo), "v"(hi));
    return r;
}

// ---------------------------------------------------------------------------
// k_prep: per o — W2 flat bf16, b2 bf16, P2/S2/sb2/qb2, Q2 (MFMA from LDS), zeros
// ---------------------------------------------------------------------------
__global__ __launch_bounds__(256)
void k_prep(const float* __restrict__ w2, const float* __restrict__ b2,
            unsigned short* __restrict__ Bf)
{
    __shared__ __align__(16) float w2s[256 * 32];
    __shared__ __align__(16) float b2s[256];
    __shared__ float pP[8][32], pS[8][32], pB[8], pQ[8];
    const int tid = threadIdx.x, lane = tid & 63, wave = tid >> 6;
    const int c = lane & 15, g = lane >> 4;
    const int o = blockIdx.x;
    const float* w2o = w2 + (size_t)o * 8192;

    #pragma unroll
    for (int q = 0; q < 8; ++q) {
        int I = wave * 8 + q;
        gll16(w2o + I * 256 + lane * 4, w2s + I * 256);
    }
    if (wave == 0) gll16(b2 + (size_t)o * 256 + lane * 4, b2s);
    asm volatile("s_waitcnt vmcnt(0)" ::: "memory");
    __syncthreads();

    unsigned short* row = Bf + (size_t)o * KB_;

    { // W2 flat bf16 [0,8192)
        const float* src = w2s + tid * 32;
        unsigned int pk[16];
        #pragma unroll
        for (int d = 0; d < 16; ++d) pk[d] = cvtpk(src[2 * d], src[2 * d + 1]);
        uint4* dst = (uint4*)(row + tid * 32);
        dst[0] = make_uint4(pk[0], pk[1], pk[2], pk[3]);
        dst[1] = make_uint4(pk[4], pk[5], pk[6], pk[7]);
        dst[2] = make_uint4(pk[8], pk[9], pk[10], pk[11]);
        dst[3] = make_uint4(pk[12], pk[13], pk[14], pk[15]);
    }
    row[8192 + tid] = f2b(b2s[tid]);   // b2 [8192,8448)

    // Q2 quadrant per wave: Q2[h,h'] = sum_i W2[i,h] W2[i,h']
    {
        const int qr = wave >> 1, qc = wave & 1;
        f32x4 acc = {0, 0, 0, 0};
        #pragma unroll
        for (int kk = 0; kk < 8; ++kk) {
            AB af, bff;
            #pragma unroll
            for (int d = 0; d < 4; ++d) {
                int i0 = kk * 32 + g * 8 + 2 * d;
                af.u[d] = cvtpk(w2s[i0 * 32 + qr * 16 + c],
                                w2s[(i0 + 1) * 32 + qr * 16 + c]);
                bff.u[d] = (qr == qc) ? af.u[d]
                         : cvtpk(w2s[i0 * 32 + qc * 16 + c],
                                 w2s[(i0 + 1) * 32 + qc * 16 + c]);
            }
            acc = __builtin_amdgcn_mfma_f32_16x16x32_bf16(af.s8, bff.s8, acc, 0, 0, 0);
        }
        #pragma unroll
        for (int j = 0; j < 4; ++j)
            row[8448 + (qr * 16 + g * 4 + j) * 32 + qc * 16 + c] = f2b(acc[j]);
    }

    { // partial P2/S2 + b2 sums
        int h = tid & 31, s = tid >> 5;
        float pa = 0.f, sa = 0.f;
        for (int i = s * 32; i < s * 32 + 32; ++i) {
            float wv = w2s[i * 32 + h];
            pa += wv * b2s[i];
            sa += wv;
        }
        pP[s][h] = pa; pS[s][h] = sa;
        if (h == 0) {
            float sb = 0.f, qb = 0.f;
            for (int i = s * 32; i < s * 32 + 32; ++i) {
                float bv = b2s[i]; sb += bv; qb += bv * bv;
            }
            pB[s] = sb; pQ[s] = qb;
        }
    }
    __syncthreads();
    if (tid < 32) {
        float p = 0.f, sv = 0.f;
        #pragma unroll
        for (int s2 = 0; s2 < 8; ++s2) { p += pP[s2][tid]; sv += pS[s2][tid]; }
        row[9472 + tid] = f2b(2.0f * p);
        row[9536 + tid] = f2b(sv);
    } else if (tid == 32) {
        float sb = 0.f;
        #pragma unroll
        for (int s2 = 0; s2 < 8; ++s2) sb += pB[s2];
        row[9568] = f2b(sb);
    } else if (tid == 33) {
        float qb = 0.f;
        #pragma unroll
        for (int s2 = 0; s2 < 8; ++s2) qb += pQ[s2];
        row[9504] = f2b(qb);
    }
    if (tid < 31) row[9505 + tid] = 0;
    { int z = tid - 31; if (z >= 0 && z < 31) row[9569 + z] = 0; }
    { int z = tid - 62; if (z >= 0 && z < 128) row[9600 + z] = 0; }
}

// ---------------------------------------------------------------------------
// ka: per token — hw (bf16, padded), xpad bf16, sx, bln (LN of bias path)
// ---------------------------------------------------------------------------
__global__ __launch_bounds__(64)
void ka_hw_bias(const float* __restrict__ x,
                const float* __restrict__ w1, const float* __restrict__ b1,
                const float* __restrict__ u1, const float* __restrict__ c1,
                const float* __restrict__ u2, const float* __restrict__ c2,
                unsigned short* __restrict__ hwbf_out,  // [T,HP]
                unsigned short* __restrict__ xp_out,    // [T,XP]
                float* __restrict__ sx_out,             // [T]
                float* __restrict__ bln_out)            // [T,256]
{
    const int t = blockIdx.x;
    const int l = threadIdx.x;

    __shared__ float xs[IN_];
    __shared__ float hb[HID_];

    float4 x4 = reinterpret_cast<const float4*>(x + (size_t)t * IN_)[l];
    reinterpret_cast<float4*>(xs)[l] = x4;

    float s = x4.x + x4.y + x4.z + x4.w;
    #pragma unroll
    for (int off = 32; off > 0; off >>= 1) s += __shfl_xor(s, off);
    if (l == 0) sx_out[t] = s;

    {
        ushort4 ux;
        ux.x = f2b(x4.x); ux.y = f2b(x4.y); ux.z = f2b(x4.z); ux.w = f2b(x4.w);
        *reinterpret_cast<ushort4*>(xp_out + (size_t)t * XP + l * 4) = ux;
    }
    __syncthreads();

    const float* wrow = (l < 32) ? (w1 + (size_t)l * IN_) : (u1 + (size_t)(l - 32) * IN_);
    float acc = (l < 32) ? b1[l] : c1[l - 32];
    #pragma unroll 8
    for (int i = 0; i < IN_; i += 4) {
        float4 w = *reinterpret_cast<const float4*>(wrow + i);
        acc += w.x * xs[i] + w.y * xs[i + 1] + w.z * xs[i + 2] + w.w * xs[i + 3];
    }
    if (l < 32) hwbf_out[(size_t)t * HP + l] = f2b(acc);
    else        hb[l - 32] = acc;
    __syncthreads();

    float bv[4];
    #pragma unroll
    for (int r = 0; r < 4; ++r) {
        const int o = l * 4 + r;
        const float* urow = u2 + (size_t)o * HID_;
        float a = c2[o];
        #pragma unroll
        for (int h = 0; h < HID_; h += 4) {
            float4 u = *reinterpret_cast<const float4*>(urow + h);
            a += u.x * hb[h] + u.y * hb[h + 1] + u.z * hb[h + 2] + u.w * hb[h + 3];
        }
        bv[r] = a;
    }
    float ss = bv[0] + bv[1] + bv[2] + bv[3];
    float qq = bv[0] * bv[0] + bv[1] * bv[1] + bv[2] * bv[2] + bv[3] * bv[3];
    #pragma unroll
    for (int off = 32; off > 0; off >>= 1) {
        ss += __shfl_xor(ss, off);
        qq += __shfl_xor(qq, off);
    }
    const float mu  = ss * (1.0f / 256.f);
    const float var = qq * (1.0f / 256.f) - mu * mu;
    const float inv = rsqrtf(var + EPS);
    #pragma unroll
    for (int r = 0; r < 4; ++r)
        bln_out[(size_t)t * 256 + l * 4 + r] = (bv[r] - mu) * inv;
}

// ---------------------------------------------------------------------------
// k_main: block = 32t x 64o, 4 waves; wave = 32t x 16o, OWNS its 16 B-rows.
// NO barriers in K-loop: per-wave triple-buffered global_load_lds staging
// (counted vmcnt), B-fragments register-prefetched one chunk ahead.
// ---------------------------------------------------------------------------
__global__ __launch_bounds__(256)
void k_main(const unsigned short* __restrict__ Bf,
            const unsigned short* __restrict__ xpad,
            const unsigned short* __restrict__ hwbf,
            const float* __restrict__ sx,
            const float* __restrict__ bln,
            float* __restrict__ y)
{
    __shared__ __align__(16) unsigned short x_sh[32 * XP];     // 16896 B
    __shared__ __align__(16) unsigned short hw_sh[32 * HP];    //  2560 B
    __shared__ __align__(16) unsigned short Bb[3][4][2048];    // 49152 B

    const int tid = threadIdx.x, lane = tid & 63, wave = tid >> 6;
    const int c = lane & 15, g = lane >> 4;
    const int b = blockIdx.x;
    // XCD swizzle: xcd = b%8; o_tile pinned to an XCD pair (1.2MB B-slice L2-resident)
    const int o_tile = (b & 7) >> 1;                 // 0..3
    const int t_tile = ((b >> 3) << 1) | (b & 1);    // 0..63
    const int t0 = t_tile * 32;
    const int orow0 = o_tile * 64 + wave * 16;       // wave's first global o

    // ---- prologue: cooperative x/hw staging, ONE barrier ----
    {
        const char* gp = (const char*)(xpad + (size_t)t0 * XP);
        for (int off = wave * 1024; off < 32 * XP * 2; off += 4096)
            if (off + lane * 16 < 32 * XP * 2)
                gll16(gp + off + lane * 16, ((char*)x_sh) + off);
        const char* gh = (const char*)(hwbf + (size_t)t0 * HP);
        for (int off = wave * 1024; off < 32 * HP * 2; off += 4096)
            if (off + lane * 16 < 32 * HP * 2)
                gll16(gh + off + lane * 16, ((char*)hw_sh) + off);
    }
    asm volatile("s_waitcnt vmcnt(0)" ::: "memory");
    __syncthreads();

    // ---- wave-private B staging (source-side XOR swizzle, linear LDS dest) ----
    const unsigned short* BfW = Bf + (size_t)orow0 * KB_;
    unsigned short* BbW[3] = { &Bb[0][wave][0], &Bb[1][wave][0], &Bb[2][wave][0] };
    auto stageB = [&](int cc, int buf) {
        #pragma unroll
        for (int q = 0; q < 4; ++q) {
            int r  = q * 4 + (lane >> 4);            // local B row 0..15
            int su = (lane & 15) ^ (r & 7);          // pre-swizzled source slot
            gll16(BfW + (size_t)r * KB_ + cc * 128 + su * 8,
                  BbW[buf] + q * 512 + lane * 8);
        }
    };
    const unsigned short* myB = &Bb[0][wave][c * 128];  // rebased per buf below
    auto readB = [&](int buf, short8* dst) {
        const unsigned short* base = &Bb[buf][wave][c * 128];
        #pragma unroll
        for (int u = 0; u < 4; ++u)
            dst[u] = *(const short8*)&base[((u * 4 + g) ^ (c & 7)) * 8];
    };
    (void)myB;

    // ---- hw fragments (constant over K) ----
    AB hp0, hp1;
    {
        uint4 v0 = *(const uint4*)&hw_sh[c * HP + g * 8];
        uint4 v1 = *(const uint4*)&hw_sh[(16 + c) * HP + g * 8];
        hp0.u[0] = v0.x; hp0.u[1] = v0.y; hp0.u[2] = v0.z; hp0.u[3] = v0.w;
        hp1.u[0] = v1.x; hp1.u[1] = v1.y; hp1.u[2] = v1.z; hp1.u[3] = v1.w;
    }
    float hwf0[8], hwf1[8];
    #pragma unroll
    for (int d = 0; d < 4; ++d) {
        hwf0[2 * d]     = __uint_as_float(hp0.u[d] << 16);
        hwf0[2 * d + 1] = __uint_as_float(hp0.u[d] & 0xFFFF0000u);
        hwf1[2 * d]     = __uint_as_float(hp1.u[d] << 16);
        hwf1[2 * d + 1] = __uint_as_float(hp1.u[d] & 0xFFFF0000u);
    }

    f32x4 dw0 = {0,0,0,0}, dw1 = {0,0,0,0};
    f32x4 qq0 = {0,0,0,0}, qq1 = {0,0,0,0};
    f32x4 sw0 = {0,0,0,0}, sw1 = {0,0,0,0};

    // ---- pipeline prologue: 3 chunks in flight, chunk 0 frags in regs ----
    stageB(0, 0); stageB(1, 1); stageB(2, 2);
    asm volatile("s_waitcnt vmcnt(8)" ::: "memory");   // chunk 0 staged
    short8 cur[4];
    readB(0, cur);

    const int xrow0 = c * XP, xrow1 = (16 + c) * XP;
    const int hrow0 = c * HP, hrow1 = (16 + c) * HP;

    for (int cc = 0; cc < 73; ++cc) {
        asm volatile("s_waitcnt vmcnt(4)" ::: "memory");   // chunk cc+1 staged
        asm volatile("s_waitcnt lgkmcnt(0)" ::: "memory"); // buf[cc%3] reads retired
        if (cc <= 71) stageB(cc + 3, (cc + 3) % 3);        // overwrite buf[cc%3]
        short8 nxt[4];
        readB((cc + 1) % 3, nxt);

        if (cc < 64) {            // MODE X: dw += (x_i * hw) x W2
            uint2 xq0 = *(const uint2*)&x_sh[xrow0 + cc * 4];
            uint2 xq1 = *(const uint2*)&x_sh[xrow1 + cc * 4];
            #pragma unroll
            for (int u = 0; u < 4; ++u) {
                unsigned int d0 = (u & 2) ? xq0.y : xq0.x;
                unsigned int d1 = (u & 2) ? xq1.y : xq1.x;
                float xv0 = __uint_as_float((u & 1) ? (d0 & 0xFFFF0000u) : (d0 << 16));
                float xv1 = __uint_as_float((u & 1) ? (d1 & 0xFFFF0000u) : (d1 << 16));
                AB a0, a1;
                #pragma unroll
                for (int d = 0; d < 4; ++d) {
                    a0.u[d] = cvtpk(xv0 * hwf0[2 * d], xv0 * hwf0[2 * d + 1]);
                    a1.u[d] = cvtpk(xv1 * hwf1[2 * d], xv1 * hwf1[2 * d + 1]);
                }
                dw0 = __builtin_amdgcn_mfma_f32_16x16x32_bf16(a0.s8, cur[u], dw0, 0, 0, 0);
                dw1 = __builtin_amdgcn_mfma_f32_16x16x32_bf16(a1.s8, cur[u], dw1, 0, 0, 0);
            }
        } else if (cc < 66) {     // MODE DX: dw += x-frag x b2
            #pragma unroll
            for (int u = 0; u < 4; ++u) {
                AB a0, a1;
                a0.s8 = *(const short8*)&x_sh[xrow0 + (cc - 64) * 128 + u * 32 + g * 8];
                a1.s8 = *(const short8*)&x_sh[xrow1 + (cc - 64) * 128 + u * 32 + g * 8];
                dw0 = __builtin_amdgcn_mfma_f32_16x16x32_bf16(a0.s8, cur[u], dw0, 0, 0, 0);
                dw1 = __builtin_amdgcn_mfma_f32_16x16x32_bf16(a1.s8, cur[u], dw1, 0, 0, 0);
            }
        } else {                  // MODE HW: qq += (hw_ho * hw) x Q2
            uint2 hq0 = *(const uint2*)&hw_sh[hrow0 + (cc - 66) * 4];
            uint2 hq1 = *(const uint2*)&hw_sh[hrow1 + (cc - 66) * 4];
            #pragma unroll
            for (int u = 0; u < 4; ++u) {
                unsigned int d0 = (u & 2) ? hq0.y : hq0.x;
                unsigned int d1 = (u & 2) ? hq1.y : hq1.x;
                float hv0 = __uint_as_float((u & 1) ? (d0 & 0xFFFF0000u) : (d0 << 16));
                float hv1 = __uint_as_float((u & 1) ? (d1 & 0xFFFF0000u) : (d1 << 16));
                AB a0, a1;
                #pragma unroll
                for (int d = 0; d < 4; ++d) {
                    a0.u[d] = cvtpk(hv0 * hwf0[2 * d], hv0 * hwf0[2 * d + 1]);
                    a1.u[d] = cvtpk(hv1 * hwf1[2 * d], hv1 * hwf1[2 * d + 1]);
                }
                qq0 = __builtin_amdgcn_mfma_f32_16x16x32_bf16(a0.s8, cur[u], qq0, 0, 0, 0);
                qq1 = __builtin_amdgcn_mfma_f32_16x16x32_bf16(a1.s8, cur[u], qq1, 0, 0, 0);
            }
        }
        #pragma unroll
        for (int u = 0; u < 4; ++u) cur[u] = nxt[u];
    }

    // ---- peeled cc=73 (last HW chunk) ----
    {
        asm volatile("s_waitcnt vmcnt(0)" ::: "memory");   // chunk 74 staged
        asm volatile("s_waitcnt lgkmcnt(0)" ::: "memory");
        short8 tl[4];
        readB(74 % 3, tl);
        uint2 hq0 = *(const uint2*)&hw_sh[hrow0 + 7 * 4];
        uint2 hq1 = *(const uint2*)&hw_sh[hrow1 + 7 * 4];
        #pragma unroll
        for (int u = 0; u < 4; ++u) {
            unsigned int d0 = (u & 2) ? hq0.y : hq0.x;
            unsigned int d1 = (u & 2) ? hq1.y : hq1.x;
            float hv0 = __uint_as_float((u & 1) ? (d0 & 0xFFFF0000u) : (d0 << 16));
            float hv1 = __uint_as_float((u & 1) ? (d1 & 0xFFFF0000u) : (d1 << 16));
            AB a0, a1;
            #pragma unroll
            for (int d = 0; d < 4; ++d) {
                a0.u[d] = cvtpk(hv0 * hwf0[2 * d], hv0 * hwf0[2 * d + 1]);
                a1.u[d] = cvtpk(hv1 * hwf1[2 * d], hv1 * hwf1[2 * d + 1]);
            }
            qq0 = __builtin_amdgcn_mfma_f32_16x16x32_bf16(a0.s8, cur[u], qq0, 0, 0, 0);
            qq1 = __builtin_amdgcn_mfma_f32_16x16x32_bf16(a1.s8, cur[u], qq1, 0, 0, 0);
        }
        #pragma unroll
        for (int u = 0; u < 4; ++u) cur[u] = tl[u];
    }

    // ---- peeled cc=74: P2 | qb2 | S2 | sb2 ----
    {
        AB e0;
        e0.u[0] = (g == 0) ? 0x3F80u : 0u;
        e0.u[1] = 0; e0.u[2] = 0; e0.u[3] = 0;
        qq0 = __builtin_amdgcn_mfma_f32_16x16x32_bf16(hp0.s8, cur[0], qq0, 0, 0, 0);
        qq1 = __builtin_amdgcn_mfma_f32_16x16x32_bf16(hp1.s8, cur[0], qq1, 0, 0, 0);
        qq0 = __builtin_amdgcn_mfma_f32_16x16x32_bf16(e0.s8,  cur[1], qq0, 0, 0, 0);
        qq1 = __builtin_amdgcn_mfma_f32_16x16x32_bf16(e0.s8,  cur[1], qq1, 0, 0, 0);
        sw0 = __builtin_amdgcn_mfma_f32_16x16x32_bf16(hp0.s8, cur[2], sw0, 0, 0, 0);
        sw1 = __builtin_amdgcn_mfma_f32_16x16x32_bf16(hp1.s8, cur[2], sw1, 0, 0, 0);
        sw0 = __builtin_amdgcn_mfma_f32_16x16x32_bf16(e0.s8,  cur[3], sw0, 0, 0, 0);
        sw1 = __builtin_amdgcn_mfma_f32_16x16x32_bf16(e0.s8,  cur[3], sw1, 0, 0, 0);
    }

    // ---- epilogue: fused LN + y ----
    const int o = orow0 + c;
    #pragma unroll
    for (int j = 0; j < 4; ++j) {
        {
            int t = t0 + g * 4 + j;
            float muv = sw0[j] * (1.f / 256.f);
            float varv = qq0[j] * (1.f / 256.f) - muv * muv;
            float inv = rsqrtf(varv + EPS);
            y[(size_t)t * 256 + o] = inv * (dw0[j] - muv * sx[t]) + bln[(size_t)t * 256 + o];
        }
        {
            int t = t0 + 16 + g * 4 + j;
            float muv = sw1[j] * (1.f / 256.f);
            float varv = qq1[j] * (1.f / 256.f) - muv * muv;
            float inv = rsqrtf(varv + EPS);
            y[(size_t)t * 256 + o] = inv * (dw1[j] - muv * sx[t]) + bln[(size_t)t * 256 + o];
        }
    }
}

// ---------------------------------------------------------------------------
extern "C" void kernel_launch(void* const* d_in, const int* in_sizes, int n_in,
                              void* d_out, int out_size, void* d_ws, size_t ws_size,
                              hipStream_t stream)
{
    (void)in_sizes; (void)n_in; (void)out_size; (void)ws_size;
    const float* x  = (const float*)d_in[0];
    const float* w1 = (const float*)d_in[1];
    const float* b1 = (const float*)d_in[2];
    const float* w2 = (const float*)d_in[3];
    const float* b2 = (const float*)d_in[4];
    const float* u1 = (const float*)d_in[5];
    const float* c1 = (const float*)d_in[6];
    const float* u2 = (const float*)d_in[7];
    const float* c2 = (const float*)d_in[8];
    float* y = (float*)d_out;

    char* ws = (char*)d_ws;
    unsigned short* Bfull = (unsigned short*)(ws);                 // 256*9728*2 = 4,980,736
    unsigned short* xpad  = (unsigned short*)(ws + 4980736);       // 2048*264*2 = 1,081,344
    unsigned short* hwbf  = (unsigned short*)(ws + 6062080);       // 2048*40*2  =   163,840
    float*          sxp   = (float*)(ws + 6225920);                // 2048*4
    float*          blnp  = (float*)(ws + 6234112);                // 2048*256*4 -> 8,331,264 total

    k_prep<<<256, 256, 0, stream>>>(w2, b2, Bfull);
    ka_hw_bias<<<T_, 64, 0, stream>>>(x, w1, b1, u1, c1, u2, c2, hwbf, xpad, sxp, blnp);

    k_main<<<256, 256, 0, stream>>>(Bfull, xpad, hwbf, sxp, blnp, y);
}